// Round 11
// baseline (125.486 us; speedup 1.0000x reference)
//
#include <hip/hip_runtime.h>
#include <hip/hip_bf16.h>

typedef unsigned short ushortT;
typedef __bf16 bf16x8 __attribute__((ext_vector_type(8)));
typedef __bf16 bf16x4 __attribute__((ext_vector_type(4)));
typedef float f32x4 __attribute__((ext_vector_type(4)));

#define T_SEQ 2048
#define DH 64
#define NH 16
#define DM 1024
#define TD 3072
#define BATCH 2
#define LOG2E 1.44269504f

// raw barrier + counted vmcnt (T4): prefetch loads stay in flight across barriers
#define BARRIER()   asm volatile("s_barrier" ::: "memory")
#define VMCNT(n)    asm volatile("s_waitcnt vmcnt(" #n ")" ::: "memory")

__device__ inline ushortT f2bf(float f){
    union { float f; unsigned int u; } a; a.f = f;
    unsigned int r = a.u + 0x7fffu + ((a.u >> 16) & 1u);
    return (ushortT)(r >> 16);
}
__device__ inline float bf2f(ushortT u){
    union { float f; unsigned int u; } a; a.u = ((unsigned int)u) << 16;
    return a.f;
}

__device__ inline void gload_lds16(const void* g, void* l){
    __builtin_amdgcn_global_load_lds((const __attribute__((address_space(1))) void*)g,
                                     (__attribute__((address_space(3))) void*)l, 16, 0, 0);
}

// ---------------- cast x (fp32 -> bf16) ----------------
__global__ __launch_bounds__(256) void cast_bf16_kernel(const float* __restrict__ in,
                                                        ushortT* __restrict__ out, int n){
    int i = (blockIdx.x * 256 + threadIdx.x) * 4;
    if (i < n){
        float4 v = *(const float4*)&in[i];
        out[i+0] = f2bf(v.x); out[i+1] = f2bf(v.y);
        out[i+2] = f2bf(v.z); out[i+3] = f2bf(v.w);
    }
}

// ---------------- transpose + cast: in (K,N) fp32 -> out (N,K) bf16 ----------------
__global__ __launch_bounds__(256) void transcast_kernel(const float* __restrict__ in,
                                                        ushortT* __restrict__ out, int K, int N){
    __shared__ float tile[64][65];
    int n0 = blockIdx.x * 64, k0 = blockIdx.y * 64;
    int tid = threadIdx.x;
    int c  = tid & 63;
    int r4 = tid >> 6;
#pragma unroll
    for (int i = 0; i < 16; i++){
        int k = r4 + i * 4;
        tile[k][c] = in[(size_t)(k0 + k) * N + n0 + c];
    }
    __syncthreads();
#pragma unroll
    for (int i = 0; i < 16; i++){
        int n = r4 + i * 4;
        out[(size_t)(n0 + n) * K + k0 + c] = f2bf(tile[c][n]);
    }
}

// ---------------- Wg transpose: in [16][d=64][e=64] f32 -> out [16][e][d] bf16 ----------------
__global__ __launch_bounds__(256) void wg_transcast_kernel(const float* __restrict__ in,
                                                           ushortT* __restrict__ out){
    __shared__ float tile[64][65];
    int h = blockIdx.x;
    int tid = threadIdx.x;
    int c = tid & 63, r4 = tid >> 6;
#pragma unroll
    for (int i = 0; i < 16; i++){
        int d = r4 + i*4;
        tile[d][c] = in[h*4096 + d*64 + c];
    }
    __syncthreads();
#pragma unroll
    for (int i = 0; i < 16; i++){
        int e = r4 + i*4;
        out[h*4096 + e*64 + c] = f2bf(tile[c][e]);   // out[h][e][d=c]
    }
}

// ---------------- bf16 MFMA GEMM (dbuf + counted vmcnt): C = A @ BT^T + bias ----------------
__device__ inline void store_out(ushortT* C, size_t i, float v){ C[i] = f2bf(v); }
__device__ inline void store_out(float*   C, size_t i, float v){ C[i] = v; }

template <typename OUT>
__global__ __launch_bounds__(256) void gemm_bf16_kernel(const ushortT* __restrict__ A,
                                                        const ushortT* __restrict__ BT,
                                                        const float* __restrict__ bias,
                                                        OUT* __restrict__ C,
                                                        int M, int N, int K){
    __shared__ __align__(16) ushortT As[2][128*32];
    __shared__ __align__(16) ushortT Bs[2][128*32];
    int tid = threadIdx.x;
    int m0 = blockIdx.x * 128;
    int n0 = blockIdx.y * 128;
    int wid = tid >> 6, lane = tid & 63;
    int l15 = lane & 15, g = lane >> 4;
    int wr = wid >> 1, wc = wid & 1;

    f32x4 acc[4][4];
#pragma unroll
    for (int i = 0; i < 4; i++)
#pragma unroll
        for (int j = 0; j < 4; j++) acc[i][j] = (f32x4){0.f,0.f,0.f,0.f};

    int srow = wid * 32 + (lane >> 2);
    int sch  = lane & 3;

#define GSTAGE(buf, k0)                                                                  \
    {                                                                                    \
        _Pragma("unroll")                                                                \
        for (int i_ = 0; i_ < 2; i_++){                                                  \
            int row_ = srow + i_ * 16;                                                   \
            const ushortT* asrc_ = A  + (size_t)(m0 + row_) * K + (k0) + sch * 8;        \
            const ushortT* bsrc_ = BT + (size_t)(n0 + row_) * K + (k0) + sch * 8;        \
            gload_lds16(asrc_, (char*)As[buf] + (wid*2 + i_) * 1024);                    \
            gload_lds16(bsrc_, (char*)Bs[buf] + (wid*2 + i_) * 1024);                    \
        }                                                                                \
    }

    GSTAGE(0, 0);

    int nk = K >> 5;
    for (int kt = 0; kt < nk; kt++){
        int buf = kt & 1;
        BARRIER();                       // (A) all waves done reading buf^1 (prev iter)
        if (kt + 1 < nk){
            GSTAGE(buf ^ 1, (kt + 1) * 32);     // 4 loads, stay in flight
            VMCNT(4);                    // tile kt (issued last iter) resident
        } else {
            VMCNT(0);
        }
        BARRIER();                       // (B) tile kt resident for all waves

        bf16x8 af[4], bfr[4];
#pragma unroll
        for (int mi = 0; mi < 4; mi++){
            int r = wr*64 + mi*16 + l15;
            af[mi]  = *(const bf16x8*)(As[buf] + r*32 + g*8);
        }
#pragma unroll
        for (int ni = 0; ni < 4; ni++){
            int r = wc*64 + ni*16 + l15;
            bfr[ni] = *(const bf16x8*)(Bs[buf] + r*32 + g*8);
        }
#pragma unroll
        for (int mi = 0; mi < 4; mi++)
#pragma unroll
            for (int ni = 0; ni < 4; ni++)
                acc[mi][ni] = __builtin_amdgcn_mfma_f32_16x16x32_bf16(af[mi], bfr[ni], acc[mi][ni], 0, 0, 0);
    }
#undef GSTAGE

#pragma unroll
    for (int mi = 0; mi < 4; mi++){
#pragma unroll
        for (int jj = 0; jj < 4; jj++){
            int mm = m0 + wr*64 + mi*16 + 4*g + jj;
#pragma unroll
            for (int ni = 0; ni < 4; ni++){
                int nn = n0 + wc*64 + ni*16 + l15;
                float v = acc[mi][ni][jj] + bias[nn];
                store_out(C, (size_t)mm * N + nn, v);
            }
        }
    }
}

// ---------------- gate (MFMA): g=sigmoid(Q @ Wg[h]); VgT[b,h,e,t] = g*v ----------------
__global__ __launch_bounds__(256) void gate_kernel(const ushortT* __restrict__ qkv,
                                                   const ushortT* __restrict__ WgT,
                                                   ushortT* __restrict__ vgT){
    __shared__ __align__(16) ushortT VT[64][72];
    int tblk = blockIdx.x, bh = blockIdx.y;
    int b = bh >> 4, h = bh & 15;
    int tid = threadIdx.x, wid = tid >> 6, lane = tid & 63;
    int l15 = lane & 15, g = lane >> 4;
    int t0 = tblk * 64;
    int tl = wid*16 + l15;

    const ushortT* qrow = qkv + ((size_t)b*T_SEQ + t0 + tl)*TD + h*DH;
    bf16x8 qf0 = *(const bf16x8*)(qrow + 8*g);
    bf16x8 qf1 = *(const bf16x8*)(qrow + 32 + 8*g);

    const ushortT* wbase = WgT + h*4096;
    const ushortT* vrow = qkv + ((size_t)b*T_SEQ + t0 + tl)*TD + 2*DM + h*DH;

#pragma unroll
    for (int ns = 0; ns < 4; ns++){
        int e = ns*16 + l15;
        bf16x8 wf0 = *(const bf16x8*)(wbase + e*64 + 8*g);
        bf16x8 wf1 = *(const bf16x8*)(wbase + e*64 + 32 + 8*g);
        f32x4 z = (f32x4){0.f,0.f,0.f,0.f};
        z = __builtin_amdgcn_mfma_f32_16x16x32_bf16(wf0, qf0, z, 0, 0, 0);
        z = __builtin_amdgcn_mfma_f32_16x16x32_bf16(wf1, qf1, z, 0, 0, 0);
        union { ushortT u[4]; uint2 v; } v4;
        v4.v = *(const uint2*)(vrow + ns*16 + 4*g);
#pragma unroll
        for (int jj = 0; jj < 4; jj++){
            float ex = __builtin_amdgcn_exp2f(-z[jj] * LOG2E);
            float gv = __builtin_amdgcn_rcpf(1.f + ex);
            VT[ns*16 + 4*g + jj][tl] = f2bf(gv * bf2f(v4.u[jj]));
        }
    }
    __syncthreads();
    for (int i = tid; i < 64*8; i += 256){
        int e = i >> 3, c8 = (i & 7) * 8;
        *(uint4*)&vgT[((size_t)bh * DH + e) * T_SEQ + t0 + c8] = *(const uint4*)&VT[e][c8];
    }
}

// ---------------- causal flash attention with gated V ----------------
// Structure as R10 (register-resident softmax/P, pi-permuted K, O^T PV, serpentine
// grid), but barriers are raw s_barrier with COUNTED vmcnt: the next tile's 4
// staging loads stay in flight across the barrier; only the final tile drains to 0.
struct QS {
    bf16x8 qf0, qf1;
    float m_, lsum;
    f32x4 acc[4];          // acc[nt][jj] = O^T[e=nt*16+4g+jj][q=l15]
};

__device__ __forceinline__ void softmax_state(f32x4* s, QS& S, bool diag,
                                              int wid, int l15, int g,
                                              bf16x8& pa0, bf16x8& pa1){
    float tmax = -INFINITY;
    if (diag){
        int qrel = wid*16 + l15;
#pragma unroll
        for (int ns = 0; ns < 4; ns++){
            int kbase = ((ns & 2) << 4) + 8*g + ((ns & 1) << 2);
#pragma unroll
            for (int jj = 0; jj < 4; jj++){
                if (kbase + jj > qrel) s[ns][jj] = -INFINITY;
                tmax = fmaxf(tmax, s[ns][jj]);
            }
        }
    } else {
#pragma unroll
        for (int ns = 0; ns < 4; ns++){
            float a = fmaxf(s[ns][0], s[ns][1]);
            float c = fmaxf(s[ns][2], s[ns][3]);
            tmax = fmaxf(tmax, fmaxf(a, c));
        }
    }
    tmax = fmaxf(tmax, __shfl_xor(tmax, 16, 64));
    tmax = fmaxf(tmax, __shfl_xor(tmax, 32, 64));

    float mnew = fmaxf(S.m_, tmax);
    float mc = mnew * LOG2E;
    float rs = 0.f;
#pragma unroll
    for (int jj = 0; jj < 4; jj++){
        float p0 = __builtin_amdgcn_exp2f(fmaf(s[0][jj], LOG2E, -mc));
        float p1 = __builtin_amdgcn_exp2f(fmaf(s[1][jj], LOG2E, -mc));
        float p2 = __builtin_amdgcn_exp2f(fmaf(s[2][jj], LOG2E, -mc));
        float p3 = __builtin_amdgcn_exp2f(fmaf(s[3][jj], LOG2E, -mc));
        rs += (p0 + p1) + (p2 + p3);
        pa0[jj]   = (__bf16)p0;
        pa0[4+jj] = (__bf16)p1;
        pa1[jj]   = (__bf16)p2;
        pa1[4+jj] = (__bf16)p3;
    }
    rs += __shfl_xor(rs, 16, 64);
    rs += __shfl_xor(rs, 32, 64);

    if (!__all(mnew == S.m_)){
        float alpha = __builtin_amdgcn_exp2f(fmaf(S.m_, LOG2E, -mc));
#pragma unroll
        for (int nt = 0; nt < 4; nt++)
#pragma unroll
            for (int jj = 0; jj < 4; jj++) S.acc[nt][jj] *= alpha;
        S.lsum *= alpha;
        S.m_ = mnew;
    }
    S.lsum += rs;
}

__device__ __forceinline__ void proc_tile1(const ushortT* __restrict__ Kb,
                                           const ushortT* __restrict__ Vb,
                                           QS& S, bool diag,
                                           int wid, int l15, int g){
    int l7 = l15 & 7;
    f32x4 s[4];
    __builtin_amdgcn_s_setprio(1);
#pragma unroll
    for (int ns = 0; ns < 4; ns++){
        int kr = ns*16 + l15;
        bf16x8 kf0 = *(const bf16x8*)(Kb + kr*64 + ((g    ) ^ l7)*8);
        bf16x8 kf1 = *(const bf16x8*)(Kb + kr*64 + ((4 + g) ^ l7)*8);
        f32x4 z = (f32x4){0.f,0.f,0.f,0.f};
        z = __builtin_amdgcn_mfma_f32_16x16x32_bf16(kf0, S.qf0, z, 0, 0, 0);
        z = __builtin_amdgcn_mfma_f32_16x16x32_bf16(kf1, S.qf1, z, 0, 0, 0);
        s[ns] = z;   // s[ns][jj] = score[kv = 32*(ns>>1) + 8g + 4*(ns&1) + jj][q=l15]
    }
    __builtin_amdgcn_s_setprio(0);

    bf16x8 pa0, pa1;
    softmax_state(s, S, diag, wid, l15, g, pa0, pa1);

    __builtin_amdgcn_s_setprio(1);
#pragma unroll
    for (int ks = 0; ks < 2; ks++){
        bf16x8 pa = ks ? pa1 : pa0;
#pragma unroll
        for (int nt = 0; nt < 4; nt++){
            bf16x8 vf = *(const bf16x8*)(Vb + (nt*16 + l15)*64 + ((ks*4 + g) ^ l7)*8);
            S.acc[nt] = __builtin_amdgcn_mfma_f32_16x16x32_bf16(vf, pa, S.acc[nt], 0, 0, 0);
        }
    }
    __builtin_amdgcn_s_setprio(0);
}

__global__ __launch_bounds__(256, 4) void attn_kernel(const ushortT* __restrict__ qkv,
                                                      const ushortT* __restrict__ vgT,
                                                      ushortT* __restrict__ obf){
    __shared__ __align__(16) ushortT Ks[2][64*64];
    __shared__ __align__(16) ushortT Vs[2][64*64];
    int id = blockIdx.x;
    int bh = id & 31;
    int y  = id >> 5;
    int ya = y & 7, yb = y >> 3;
    int qblk = yb*8 + ((yb & 1) ? 7 - ya : ya);   // co-resident qblk sums constant
    int b = bh >> 4, h = bh & 15;
    int tid = threadIdx.x, wid = tid >> 6, lane = tid & 63;
    int l15 = lane & 15, g = lane >> 4;

    const ushortT* Kg = qkv + (size_t)b * T_SEQ * TD + DM + h * DH;
    const ushortT* Vg = vgT + (size_t)bh * DH * T_SEQ;

    // staging: 256 threads x 16B x 2 issues = one 64x64 bf16 tile per buffer
    int st_row0 = wid*8 + (lane >> 3);            // 0..31, +32 on second issue
    int st_c    = (lane & 7) ^ ((lane >> 3) & 7); // col-chunk XOR swizzle

#define STAGE_TILE(bufidx, kv0)                                                          \
    {                                                                                    \
        _Pragma("unroll")                                                                \
        for (int i_ = 0; i_ < 2; i_++){                                                  \
            int row_  = st_row0 + i_*32;                                                 \
            int prow_ = (row_ & 0x20) | ((row_ & 0x0C) << 1) |                           \
                        ((row_ & 0x10) >> 2) | (row_ & 3);                               \
            const ushortT* ksrc_ = Kg + (size_t)((kv0) + prow_) * TD + st_c*8;           \
            const ushortT* vsrc_ = Vg + (size_t)row_ * T_SEQ + (kv0) + st_c*8;           \
            gload_lds16(ksrc_, (char*)Ks[bufidx] + wid*1024 + i_*4096);                  \
            gload_lds16(vsrc_, (char*)Vs[bufidx] + wid*1024 + i_*4096);                  \
        }                                                                                \
    }

    QS S;
    {
        int qrow = qblk*64 + wid*16 + l15;
        const ushortT* qb = qkv + ((size_t)b * T_SEQ + qrow) * TD + h * DH;
        S.qf0 = *(const bf16x8*)(qb + 8*g);
        S.qf1 = *(const bf16x8*)(qb + 32 + 8*g);
#pragma unroll
        for (int j = 0; j < 8; j++){
            S.qf0[j] = (__bf16)((float)S.qf0[j] * 0.125f);
            S.qf1[j] = (__bf16)((float)S.qf1[j] * 0.125f);
        }
        S.m_ = -INFINITY; S.lsum = 0.f;
#pragma unroll
        for (int nt = 0; nt < 4; nt++) S.acc[nt] = (f32x4){0.f,0.f,0.f,0.f};
    }

    STAGE_TILE(0, 0);

    for (int t = 0; t <= qblk; t++){
        int buf = t & 1;
        BARRIER();                       // (A) all waves done reading buf^1 (prev iter)
        if (t < qblk){
            STAGE_TILE(buf ^ 1, (t+1)*64);   // 4 loads, stay in flight across barrier
            VMCNT(4);                    // tile t (issued last iter) fully resident
        } else {
            VMCNT(0);
        }
        BARRIER();                       // (B) tile t resident for all waves
        proc_tile1(Ks[buf], Vs[buf], S, t == qblk, wid, l15, g);
    }
#undef STAGE_TILE

    float inv = 1.f / S.lsum;
    size_t orow = ((size_t)b * T_SEQ + qblk*64 + wid*16 + l15) * DM + h*DH;
#pragma unroll
    for (int nt = 0; nt < 4; nt++){
        union { ushortT u[4]; uint2 v; } pk;
#pragma unroll
        for (int jj = 0; jj < 4; jj++) pk.u[jj] = f2bf(S.acc[nt][jj] * inv);
        *(uint2*)&obf[orow + nt*16 + 4*g] = pk.v;
    }
}

extern "C" void kernel_launch(void* const* d_in, const int* in_sizes, int n_in,
                              void* d_out, int out_size, void* d_ws, size_t ws_size,
                              hipStream_t stream){
    const float* x    = (const float*)d_in[0];
    const float* Wqkv = (const float*)d_in[1];
    const float* bqkv = (const float*)d_in[2];
    const float* Wg   = (const float*)d_in[3];
    const float* Wout = (const float*)d_in[4];
    const float* bout = (const float*)d_in[5];

    char* ws = (char*)d_ws;
    ushortT* xbf   = (ushortT*)(ws);                 //  8 MB : (4096,1024) bf16
    ushortT* wqkvT = (ushortT*)(ws + 8388608);       //  6 MB : (3072,1024) bf16
    ushortT* woutT = (ushortT*)(ws + 14680064);      //  2 MB : (1024,1024) bf16
    ushortT* qkvb  = (ushortT*)(ws + 16777216);      // 24 MB : (4096,3072) bf16
    ushortT* vgT   = (ushortT*)(ws + 41943040);      //  8 MB : (32,64,2048) bf16
    ushortT* obf   = (ushortT*)(ws + 50331648);      //  8 MB : (4096,1024) bf16
    ushortT* wgT   = (ushortT*)(ws + 58720256);      // 128KB : (16,64,64) bf16

    cast_bf16_kernel<<<4096, 256, 0, stream>>>(x, xbf, 4194304);
    transcast_kernel<<<dim3(48,16), 256, 0, stream>>>(Wqkv, wqkvT, 1024, 3072);
    transcast_kernel<<<dim3(16,16), 256, 0, stream>>>(Wout, woutT, 1024, 1024);
    wg_transcast_kernel<<<16, 256, 0, stream>>>(Wg, wgT);
    gemm_bf16_kernel<ushortT><<<dim3(32,24), 256, 0, stream>>>(xbf, wqkvT, bqkv, qkvb, 4096, 3072, 1024);
    gate_kernel<<<dim3(32,32), 256, 0, stream>>>(qkvb, wgT, vgT);
    attn_kernel<<<1024, 256, 0, stream>>>(qkvb, vgT, obf);
    gemm_bf16_kernel<float><<<dim3(32,8), 256, 0, stream>>>(obf, woutT, bout, (float*)d_out, 4096, 1024, 1024);
}

// Round 12
// 124.699 us; speedup vs baseline: 1.0063x; 1.0063x over previous
//
#include <hip/hip_runtime.h>
#include <hip/hip_bf16.h>

typedef unsigned short ushortT;
typedef __bf16 bf16x8 __attribute__((ext_vector_type(8)));
typedef __bf16 bf16x4 __attribute__((ext_vector_type(4)));
typedef float f32x4 __attribute__((ext_vector_type(4)));

#define T_SEQ 2048
#define DH 64
#define NH 16
#define DM 1024
#define TD 3072
#define BATCH 2
#define LOG2E 1.44269504f

#define BARRIER()   asm volatile("s_barrier" ::: "memory")
#define VMCNT(n)    asm volatile("s_waitcnt vmcnt(" #n ")" ::: "memory")

__device__ inline ushortT f2bf(float f){
    union { float f; unsigned int u; } a; a.f = f;
    unsigned int r = a.u + 0x7fffu + ((a.u >> 16) & 1u);
    return (ushortT)(r >> 16);
}
__device__ inline float bf2f(ushortT u){
    union { float f; unsigned int u; } a; a.u = ((unsigned int)u) << 16;
    return a.f;
}

__device__ inline void gload_lds16(const void* g, void* l){
    __builtin_amdgcn_global_load_lds((const __attribute__((address_space(1))) void*)g,
                                     (__attribute__((address_space(3))) void*)l, 16, 0, 0);
}

// ---------------- cast x (fp32 -> bf16) ----------------
__global__ __launch_bounds__(256) void cast_bf16_kernel(const float* __restrict__ in,
                                                        ushortT* __restrict__ out, int n){
    int i = (blockIdx.x * 256 + threadIdx.x) * 4;
    if (i < n){
        float4 v = *(const float4*)&in[i];
        out[i+0] = f2bf(v.x); out[i+1] = f2bf(v.y);
        out[i+2] = f2bf(v.z); out[i+3] = f2bf(v.w);
    }
}

// ---------------- transpose + cast: in (K,N) fp32 -> out (N,K) bf16 ----------------
__global__ __launch_bounds__(256) void transcast_kernel(const float* __restrict__ in,
                                                        ushortT* __restrict__ out, int K, int N){
    __shared__ float tile[64][65];
    int n0 = blockIdx.x * 64, k0 = blockIdx.y * 64;
    int tid = threadIdx.x;
    int c  = tid & 63;
    int r4 = tid >> 6;
#pragma unroll
    for (int i = 0; i < 16; i++){
        int k = r4 + i * 4;
        tile[k][c] = in[(size_t)(k0 + k) * N + n0 + c];
    }
    __syncthreads();
#pragma unroll
    for (int i = 0; i < 16; i++){
        int n = r4 + i * 4;
        out[(size_t)(n0 + n) * K + k0 + c] = f2bf(tile[c][n]);
    }
}

// ---------------- Wg transpose: in [16][d=64][e=64] f32 -> out [16][e][d] bf16 ----------------
__global__ __launch_bounds__(256) void wg_transcast_kernel(const float* __restrict__ in,
                                                           ushortT* __restrict__ out){
    __shared__ float tile[64][65];
    int h = blockIdx.x;
    int tid = threadIdx.x;
    int c = tid & 63, r4 = tid >> 6;
#pragma unroll
    for (int i = 0; i < 16; i++){
        int d = r4 + i*4;
        tile[d][c] = in[h*4096 + d*64 + c];
    }
    __syncthreads();
#pragma unroll
    for (int i = 0; i < 16; i++){
        int e = r4 + i*4;
        out[h*4096 + e*64 + c] = f2bf(tile[c][e]);   // out[h][e][d=c]
    }
}

// ---------------- bf16 MFMA GEMM (dbuf + counted vmcnt): C = A @ BT^T + bias ----------------
__device__ inline void store_out(ushortT* C, size_t i, float v){ C[i] = f2bf(v); }
__device__ inline void store_out(float*   C, size_t i, float v){ C[i] = v; }

template <typename OUT>
__global__ __launch_bounds__(256) void gemm_bf16_kernel(const ushortT* __restrict__ A,
                                                        const ushortT* __restrict__ BT,
                                                        const float* __restrict__ bias,
                                                        OUT* __restrict__ C,
                                                        int M, int N, int K){
    __shared__ __align__(16) ushortT As[2][128*32];
    __shared__ __align__(16) ushortT Bs[2][128*32];
    int tid = threadIdx.x;
    int m0 = blockIdx.x * 128;
    int n0 = blockIdx.y * 128;
    int wid = tid >> 6, lane = tid & 63;
    int l15 = lane & 15, g = lane >> 4;
    int wr = wid >> 1, wc = wid & 1;

    f32x4 acc[4][4];
#pragma unroll
    for (int i = 0; i < 4; i++)
#pragma unroll
        for (int j = 0; j < 4; j++) acc[i][j] = (f32x4){0.f,0.f,0.f,0.f};

    int srow = wid * 32 + (lane >> 2);
    int sch  = lane & 3;

#define GSTAGE(buf, k0)                                                                  \
    {                                                                                    \
        _Pragma("unroll")                                                                \
        for (int i_ = 0; i_ < 2; i_++){                                                  \
            int row_ = srow + i_ * 16;                                                   \
            const ushortT* asrc_ = A  + (size_t)(m0 + row_) * K + (k0) + sch * 8;        \
            const ushortT* bsrc_ = BT + (size_t)(n0 + row_) * K + (k0) + sch * 8;        \
            gload_lds16(asrc_, (char*)As[buf] + (wid*2 + i_) * 1024);                    \
            gload_lds16(bsrc_, (char*)Bs[buf] + (wid*2 + i_) * 1024);                    \
        }                                                                                \
    }

    GSTAGE(0, 0);

    int nk = K >> 5;
    for (int kt = 0; kt < nk; kt++){
        int buf = kt & 1;
        BARRIER();
        if (kt + 1 < nk){
            GSTAGE(buf ^ 1, (kt + 1) * 32);
            VMCNT(4);
        } else {
            VMCNT(0);
        }
        BARRIER();

        bf16x8 af[4], bfr[4];
#pragma unroll
        for (int mi = 0; mi < 4; mi++){
            int r = wr*64 + mi*16 + l15;
            af[mi]  = *(const bf16x8*)(As[buf] + r*32 + g*8);
        }
#pragma unroll
        for (int ni = 0; ni < 4; ni++){
            int r = wc*64 + ni*16 + l15;
            bfr[ni] = *(const bf16x8*)(Bs[buf] + r*32 + g*8);
        }
#pragma unroll
        for (int mi = 0; mi < 4; mi++)
#pragma unroll
            for (int ni = 0; ni < 4; ni++)
                acc[mi][ni] = __builtin_amdgcn_mfma_f32_16x16x32_bf16(af[mi], bfr[ni], acc[mi][ni], 0, 0, 0);
    }
#undef GSTAGE

#pragma unroll
    for (int mi = 0; mi < 4; mi++){
#pragma unroll
        for (int jj = 0; jj < 4; jj++){
            int mm = m0 + wr*64 + mi*16 + 4*g + jj;
#pragma unroll
            for (int ni = 0; ni < 4; ni++){
                int nn = n0 + wc*64 + ni*16 + l15;
                float v = acc[mi][ni][jj] + bias[nn];
                store_out(C, (size_t)mm * N + nn, v);
            }
        }
    }
}

// ---------------- gate (MFMA): g=sigmoid(Q @ Wg[h]); VgT[b,h,e,t] = g*v ----------------
__global__ __launch_bounds__(256) void gate_kernel(const ushortT* __restrict__ qkv,
                                                   const ushortT* __restrict__ WgT,
                                                   ushortT* __restrict__ vgT){
    __shared__ __align__(16) ushortT VT[64][72];
    int tblk = blockIdx.x, bh = blockIdx.y;
    int b = bh >> 4, h = bh & 15;
    int tid = threadIdx.x, wid = tid >> 6, lane = tid & 63;
    int l15 = lane & 15, g = lane >> 4;
    int t0 = tblk * 64;
    int tl = wid*16 + l15;

    const ushortT* qrow = qkv + ((size_t)b*T_SEQ + t0 + tl)*TD + h*DH;
    bf16x8 qf0 = *(const bf16x8*)(qrow + 8*g);
    bf16x8 qf1 = *(const bf16x8*)(qrow + 32 + 8*g);

    const ushortT* wbase = WgT + h*4096;
    const ushortT* vrow = qkv + ((size_t)b*T_SEQ + t0 + tl)*TD + 2*DM + h*DH;

#pragma unroll
    for (int ns = 0; ns < 4; ns++){
        int e = ns*16 + l15;
        bf16x8 wf0 = *(const bf16x8*)(wbase + e*64 + 8*g);
        bf16x8 wf1 = *(const bf16x8*)(wbase + e*64 + 32 + 8*g);
        f32x4 z = (f32x4){0.f,0.f,0.f,0.f};
        z = __builtin_amdgcn_mfma_f32_16x16x32_bf16(wf0, qf0, z, 0, 0, 0);
        z = __builtin_amdgcn_mfma_f32_16x16x32_bf16(wf1, qf1, z, 0, 0, 0);
        union { ushortT u[4]; uint2 v; } v4;
        v4.v = *(const uint2*)(vrow + ns*16 + 4*g);
#pragma unroll
        for (int jj = 0; jj < 4; jj++){
            float ex = __builtin_amdgcn_exp2f(-z[jj] * LOG2E);
            float gv = __builtin_amdgcn_rcpf(1.f + ex);
            VT[ns*16 + 4*g + jj][tl] = f2bf(gv * bf2f(v4.u[jj]));
        }
    }
    __syncthreads();
    for (int i = tid; i < 64*8; i += 256){
        int e = i >> 3, c8 = (i & 7) * 8;
        *(uint4*)&vgT[((size_t)bh * DH + e) * T_SEQ + t0 + c8] = *(const uint4*)&VT[e][c8];
    }
}

// ---------------- causal flash attention with gated V -- kv-parity split ----------------
// Block = 512 thr / 8 waves, ONE qblk. Waves 0-3: even kv tiles; waves 4-7: odd kv
// tiles (same 64 q-rows, independent online-softmax partials). Rounds = ceil((qblk+1)/2)
// <= 16 (was 32): R6-R11 showed time ~ 1.45us x max-rounds regardless of per-round work.
// Final exact flash-combine of the two partials through LDS (reuses K buffers).
// Register-resident P (pi-permuted K rows), O^T PV -> all softmax state lane-local.
struct QS {
    bf16x8 qf0, qf1;
    float m_, lsum;
    f32x4 acc[4];          // acc[nt][jj] = O^T[e=nt*16+4g+jj][q=l15]
};

__device__ __forceinline__ void softmax_state(f32x4* s, QS& S, bool diag,
                                              int wq, int l15, int g,
                                              bf16x8& pa0, bf16x8& pa1){
    float tmax = -INFINITY;
    if (diag){
        int qrel = wq*16 + l15;
#pragma unroll
        for (int ns = 0; ns < 4; ns++){
            int kbase = ((ns & 2) << 4) + 8*g + ((ns & 1) << 2);
#pragma unroll
            for (int jj = 0; jj < 4; jj++){
                if (kbase + jj > qrel) s[ns][jj] = -INFINITY;
                tmax = fmaxf(tmax, s[ns][jj]);
            }
        }
    } else {
#pragma unroll
        for (int ns = 0; ns < 4; ns++){
            float a = fmaxf(s[ns][0], s[ns][1]);
            float c = fmaxf(s[ns][2], s[ns][3]);
            tmax = fmaxf(tmax, fmaxf(a, c));
        }
    }
    tmax = fmaxf(tmax, __shfl_xor(tmax, 16, 64));
    tmax = fmaxf(tmax, __shfl_xor(tmax, 32, 64));

    float mnew = fmaxf(S.m_, tmax);
    float mc = mnew * LOG2E;
    float rs = 0.f;
#pragma unroll
    for (int jj = 0; jj < 4; jj++){
        float p0 = __builtin_amdgcn_exp2f(fmaf(s[0][jj], LOG2E, -mc));
        float p1 = __builtin_amdgcn_exp2f(fmaf(s[1][jj], LOG2E, -mc));
        float p2 = __builtin_amdgcn_exp2f(fmaf(s[2][jj], LOG2E, -mc));
        float p3 = __builtin_amdgcn_exp2f(fmaf(s[3][jj], LOG2E, -mc));
        rs += (p0 + p1) + (p2 + p3);
        pa0[jj]   = (__bf16)p0;
        pa0[4+jj] = (__bf16)p1;
        pa1[jj]   = (__bf16)p2;
        pa1[4+jj] = (__bf16)p3;
    }
    rs += __shfl_xor(rs, 16, 64);
    rs += __shfl_xor(rs, 32, 64);

    if (!__all(mnew == S.m_)){
        float alpha = __builtin_amdgcn_exp2f(fmaf(S.m_, LOG2E, -mc));
#pragma unroll
        for (int nt = 0; nt < 4; nt++)
#pragma unroll
            for (int jj = 0; jj < 4; jj++) S.acc[nt][jj] *= alpha;
        S.lsum *= alpha;
        S.m_ = mnew;
    }
    S.lsum += rs;
}

__device__ __forceinline__ void proc_tile1(const ushortT* __restrict__ Kb,
                                           const ushortT* __restrict__ Vb,
                                           QS& S, bool diag,
                                           int wq, int l15, int g){
    int l7 = l15 & 7;
    f32x4 s[4];
    __builtin_amdgcn_s_setprio(1);
#pragma unroll
    for (int ns = 0; ns < 4; ns++){
        int kr = ns*16 + l15;
        bf16x8 kf0 = *(const bf16x8*)(Kb + kr*64 + ((g    ) ^ l7)*8);
        bf16x8 kf1 = *(const bf16x8*)(Kb + kr*64 + ((4 + g) ^ l7)*8);
        f32x4 z = (f32x4){0.f,0.f,0.f,0.f};
        z = __builtin_amdgcn_mfma_f32_16x16x32_bf16(kf0, S.qf0, z, 0, 0, 0);
        z = __builtin_amdgcn_mfma_f32_16x16x32_bf16(kf1, S.qf1, z, 0, 0, 0);
        s[ns] = z;   // s[ns][jj] = score[kv = 32*(ns>>1) + 8g + 4*(ns&1) + jj][q=l15]
    }
    __builtin_amdgcn_s_setprio(0);

    bf16x8 pa0, pa1;
    softmax_state(s, S, diag, wq, l15, g, pa0, pa1);

    __builtin_amdgcn_s_setprio(1);
#pragma unroll
    for (int ks = 0; ks < 2; ks++){
        bf16x8 pa = ks ? pa1 : pa0;
#pragma unroll
        for (int nt = 0; nt < 4; nt++){
            bf16x8 vf = *(const bf16x8*)(Vb + (nt*16 + l15)*64 + ((ks*4 + g) ^ l7)*8);
            S.acc[nt] = __builtin_amdgcn_mfma_f32_16x16x32_bf16(vf, pa, S.acc[nt], 0, 0, 0);
        }
    }
    __builtin_amdgcn_s_setprio(0);
}

__global__ __launch_bounds__(512, 4) void attn_kernel(const ushortT* __restrict__ qkv,
                                                      const ushortT* __restrict__ vgT,
                                                      ushortT* __restrict__ obf){
    __shared__ __align__(16) ushortT Ks[2][2][64*64];   // [dbuf][parity] 32 KB
    __shared__ __align__(16) ushortT Vs[2][2][64*64];   // 32 KB
    int id = blockIdx.x;
    int bh = id & 31;                       // same-bh blocks share an XCD (32%8==0)
    int y  = id >> 5;
    int ya = y & 7, yb = y >> 3;
    int qblk = yb*8 + ((yb & 1) ? 7 - ya : ya);
    int b = bh >> 4, h = bh & 15;
    int tid = threadIdx.x, wid = tid >> 6, lane = tid & 63;
    int l15 = lane & 15, g = lane >> 4;
    int grp = wid >> 2;                     // kv parity group
    int wq  = wid & 3;                      // q-row group (rows wq*16 + l15)

    const ushortT* Kg = qkv + (size_t)b * T_SEQ * TD + DM + h * DH;
    const ushortT* Vg = vgT + (size_t)bh * DH * T_SEQ;

    // staging: 512 threads x 16B = one full 64x64 tile per issue
    int st_row  = tid >> 3;                               // 0..63
    int st_c    = (tid & 7) ^ (st_row & 7);               // XOR col swizzle
    int st_prow = (st_row & 0x20) | ((st_row & 0x0C) << 1) |
                  ((st_row & 0x10) >> 2) | (st_row & 3);  // pi(row) for K

#define STAGE_PAIR(buf, rr)                                                              \
    {                                                                                    \
        int keT_ = 2*(rr);     if (keT_ > qblk) keT_ = qblk;                             \
        int koT_ = 2*(rr) + 1; if (koT_ > qblk) koT_ = qblk;                             \
        int kvE_ = keT_ * 64, kvO_ = koT_ * 64;                                          \
        gload_lds16(Kg + (size_t)(kvE_ + st_prow) * TD + st_c*8,                         \
                    (char*)Ks[buf][0] + wid*1024);                                       \
        gload_lds16(Kg + (size_t)(kvO_ + st_prow) * TD + st_c*8,                         \
                    (char*)Ks[buf][1] + wid*1024);                                       \
        gload_lds16(Vg + (size_t)st_row * T_SEQ + kvE_ + st_c*8,                         \
                    (char*)Vs[buf][0] + wid*1024);                                       \
        gload_lds16(Vg + (size_t)st_row * T_SEQ + kvO_ + st_c*8,                         \
                    (char*)Vs[buf][1] + wid*1024);                                       \
    }

    QS S;
    {
        int qrow = qblk*64 + wq*16 + l15;
        const ushortT* qb = qkv + ((size_t)b * T_SEQ + qrow) * TD + h * DH;
        S.qf0 = *(const bf16x8*)(qb + 8*g);
        S.qf1 = *(const bf16x8*)(qb + 32 + 8*g);
#pragma unroll
        for (int j = 0; j < 8; j++){
            S.qf0[j] = (__bf16)((float)S.qf0[j] * 0.125f);
            S.qf1[j] = (__bf16)((float)S.qf1[j] * 0.125f);
        }
        S.m_ = -INFINITY; S.lsum = 0.f;
#pragma unroll
        for (int nt = 0; nt < 4; nt++) S.acc[nt] = (f32x4){0.f,0.f,0.f,0.f};
    }

    int nr = (qblk >> 1) + 1;               // ceil((qblk+1)/2)
    STAGE_PAIR(0, 0);

    for (int r = 0; r < nr; r++){
        int buf = r & 1;
        BARRIER();                          // all waves done reading buf^1
        if (r + 1 < nr){
            STAGE_PAIR(buf ^ 1, r + 1);     // 4 loads stay in flight across barrier
            VMCNT(4);                       // round r's tiles resident
        } else {
            VMCNT(0);
        }
        BARRIER();
        int t = 2*r + grp;
        if (t <= qblk)
            proc_tile1(Ks[buf][grp], Vs[buf][grp], S, t == qblk, wq, l15, g);
    }
#undef STAGE_PAIR

    // ---- exact flash-combine of the two kv-parity partials (LDS exchange) ----
    BARRIER();
    float* accL = (float*)&Ks[0][0][0];     // [wq][e=64][q=16] f32 = 16 KB
    float* mlL  = (float*)&Vs[0][0][0];     // [wq][2][16] f32
    if (grp == 1){
        mlL[(wq*2 + 0)*16 + l15] = S.m_;
        mlL[(wq*2 + 1)*16 + l15] = S.lsum;
#pragma unroll
        for (int nt = 0; nt < 4; nt++)
#pragma unroll
            for (int jj = 0; jj < 4; jj++)
                accL[wq*1024 + (nt*16 + 4*g + jj)*16 + l15] = S.acc[nt][jj];
    }
    BARRIER();
    if (grp == 0){
        float m2 = mlL[(wq*2 + 0)*16 + l15];
        float l2 = mlL[(wq*2 + 1)*16 + l15];
        float mm = fmaxf(S.m_, m2);
        float a1 = __builtin_amdgcn_exp2f((S.m_ - mm) * LOG2E);
        float a2 = __builtin_amdgcn_exp2f((m2  - mm) * LOG2E);
        float inv = 1.f / (S.lsum * a1 + l2 * a2);
        float ia1 = a1 * inv, ia2 = a2 * inv;
        size_t orow = ((size_t)b * T_SEQ + qblk*64 + wq*16 + l15) * DM + h*DH;
#pragma unroll
        for (int nt = 0; nt < 4; nt++){
            union { ushortT u[4]; uint2 v; } pk;
#pragma unroll
            for (int jj = 0; jj < 4; jj++){
                float o2 = accL[wq*1024 + (nt*16 + 4*g + jj)*16 + l15];
                pk.u[jj] = f2bf(S.acc[nt][jj] * ia1 + o2 * ia2);
            }
            *(uint2*)&obf[orow + nt*16 + 4*g] = pk.v;
        }
    }
}

extern "C" void kernel_launch(void* const* d_in, const int* in_sizes, int n_in,
                              void* d_out, int out_size, void* d_ws, size_t ws_size,
                              hipStream_t stream){
    const float* x    = (const float*)d_in[0];
    const float* Wqkv = (const float*)d_in[1];
    const float* bqkv = (const float*)d_in[2];
    const float* Wg   = (const float*)d_in[3];
    const float* Wout = (const float*)d_in[4];
    const float* bout = (const float*)d_in[5];

    char* ws = (char*)d_ws;
    ushortT* xbf   = (ushortT*)(ws);                 //  8 MB : (4096,1024) bf16
    ushortT* wqkvT = (ushortT*)(ws + 8388608);       //  6 MB : (3072,1024) bf16
    ushortT* woutT = (ushortT*)(ws + 14680064);      //  2 MB : (1024,1024) bf16
    ushortT* qkvb  = (ushortT*)(ws + 16777216);      // 24 MB : (4096,3072) bf16
    ushortT* vgT   = (ushortT*)(ws + 41943040);      //  8 MB : (32,64,2048) bf16
    ushortT* obf   = (ushortT*)(ws + 50331648);      //  8 MB : (4096,1024) bf16
    ushortT* wgT   = (ushortT*)(ws + 58720256);      // 128KB : (16,64,64) bf16

    cast_bf16_kernel<<<4096, 256, 0, stream>>>(x, xbf, 4194304);
    transcast_kernel<<<dim3(48,16), 256, 0, stream>>>(Wqkv, wqkvT, 1024, 3072);
    transcast_kernel<<<dim3(16,16), 256, 0, stream>>>(Wout, woutT, 1024, 1024);
    wg_transcast_kernel<<<16, 256, 0, stream>>>(Wg, wgT);
    gemm_bf16_kernel<ushortT><<<dim3(32,24), 256, 0, stream>>>(xbf, wqkvT, bqkv, qkvb, 4096, 3072, 1024);
    gate_kernel<<<dim3(32,32), 256, 0, stream>>>(qkvb, wgT, vgT);
    attn_kernel<<<1024, 512, 0, stream>>>(qkvb, vgT, obf);
    gemm_bf16_kernel<float><<<dim3(32,8), 256, 0, stream>>>(obf, woutT, bout, (float*)d_out, 4096, 1024, 1024);
}